// Round 11
// baseline (366.232 us; speedup 1.0000x reference)
//
#include <hip/hip_runtime.h>
#include <stdint.h>

typedef unsigned short u16;
typedef __attribute__((ext_vector_type(8))) short bf16x8;
typedef __attribute__((ext_vector_type(4))) float f32x4;
typedef __attribute__((ext_vector_type(4))) uint32_t u32x4;

#define MFMA16(a,b,c) __builtin_amdgcn_mfma_f32_16x16x32_bf16(a,b,c,0,0,0)

__device__ __forceinline__ float bf2f(u16 u){
  union { float f; uint32_t i; } c; c.i = ((uint32_t)u)<<16; return c.f;
}
__device__ __forceinline__ u16 f2bf(float f){
  union { float f; uint32_t i; } c; c.f = f;
  uint32_t r = c.i + 0x7FFFu + ((c.i>>16)&1u);
  return (u16)(r>>16);
}
// pure-C packed bf16 pair (RNE) — NO inline asm (R10: asm cvt_pk miscompiles
// under high register pressure; pure-C verified PASS)
__device__ __forceinline__ uint32_t pack_bf16(float a, float b){
  return (uint32_t)f2bf(a) | ((uint32_t)f2bf(b)<<16);
}

// ---------------- convert x (fp32 -> bf16) ----------------
__global__ void cvt_x_kernel(const float* __restrict__ x, u16* __restrict__ xbf){
  int i = blockIdx.x*256 + threadIdx.x;
  float4 v = ((const float4* __restrict__)x)[i];
  uint2 pk;
  pk.x = (uint32_t)f2bf(v.x) | ((uint32_t)f2bf(v.y)<<16);
  pk.y = (uint32_t)f2bf(v.z) | ((uint32_t)f2bf(v.w)<<16);
  ((uint2*)xbf)[i] = pk;
}

// ------------- transpose + convert weights: W[k][n] -> Wt[n][k] bf16 -------------
__global__ void cvt_w_kernel(const float* __restrict__ Wq, const float* __restrict__ Wk,
                             const float* __restrict__ Wv, const float* __restrict__ Wo,
                             u16* __restrict__ wt, u16* __restrict__ wot){
  __shared__ float t[32][33];
  int w = blockIdx.z;
  const float* W = (w==0)?Wq:(w==1)?Wk:(w==2)?Wv:Wo;
  u16* dst = (w<3) ? (wt + (size_t)w*640*640) : wot;
  int k0 = blockIdx.x*32, n0 = blockIdx.y*32;
  int tx = threadIdx.x, ty = threadIdx.y;
  for (int j=ty; j<32; j+=8) t[j][tx] = W[(size_t)(k0+j)*640 + n0+tx];
  __syncthreads();
  for (int j=ty; j<32; j+=8) dst[(size_t)(n0+j)*640 + k0+tx] = f2bf(t[tx][j]);
}

// ---------------- GEMM: C[12288x640] = A[12288x640] * Bt^T, bf16 MFMA ----------------
template<int MODE>
__global__ __launch_bounds__(256,2) void gemm_kernel(
    const u16* __restrict__ A, const u16* __restrict__ Bt,
    const float* __restrict__ bias,
    u16* __restrict__ Oq, u16* __restrict__ Ok, u16* __restrict__ Vt,
    float* __restrict__ Cout)
{
  __shared__ u16 As[128*64];
  __shared__ u16 Bs[128*64];
  const int n0 = blockIdx.x*128;
  const int m0 = blockIdx.y*128;
  const int w  = blockIdx.z;
  const u16* Bw = Bt + (size_t)w*640*640;
  const int tid = threadIdx.x;
  const int wid = tid>>6, lane = tid&63;
  const int wr = wid>>1, wc = wid&1;
  const int lrow = lane&15, lk = (lane>>4)<<3;

  f32x4 acc[4][4];
  #pragma unroll
  for (int i=0;i<4;++i)
    #pragma unroll
    for (int j=0;j<4;++j) acc[i][j] = (f32x4)0.0f;

  const int srow = wid*32 + (lane>>3);
  const int schunk = (lane&7)*8;

  for (int kt=0; kt<10; ++kt){
    const int k0 = kt*64;
    __syncthreads();
    #pragma unroll
    for (int j=0;j<4;++j){
      const u16* gA = A  + (size_t)(m0 + srow + j*8)*640 + k0 + schunk;
      const u16* gB = Bw + (size_t)(n0 + srow + j*8)*640 + k0 + schunk;
      __builtin_amdgcn_global_load_lds((const __attribute__((address_space(1))) void*)gA,
          (__attribute__((address_space(3))) void*)(As + (wid*32 + j*8)*64), 16, 0, 0);
      __builtin_amdgcn_global_load_lds((const __attribute__((address_space(1))) void*)gB,
          (__attribute__((address_space(3))) void*)(Bs + (wid*32 + j*8)*64), 16, 0, 0);
    }
    __syncthreads();
    #pragma unroll
    for (int kk=0; kk<2; ++kk){
      bf16x8 af[4], bfr[4];
      #pragma unroll
      for (int mi=0;mi<4;++mi)
        af[mi] = *(const bf16x8*)(As + (wr*64 + mi*16 + lrow)*64 + kk*32 + lk);
      #pragma unroll
      for (int ni=0;ni<4;++ni)
        bfr[ni] = *(const bf16x8*)(Bs + (wc*64 + ni*16 + lrow)*64 + kk*32 + lk);
      #pragma unroll
      for (int mi=0;mi<4;++mi)
        #pragma unroll
        for (int ni=0;ni<4;++ni)
          acc[mi][ni] = MFMA16(af[mi], bfr[ni], acc[mi][ni]);
    }
  }

  if (MODE==0){
    int hh4[4], dd4[4];
    #pragma unroll
    for (int ni=0;ni<4;++ni){
      int nn = n0 + wc*64 + ni*16 + lrow;
      hh4[ni] = nn/80; dd4[ni] = nn - hh4[ni]*80;
    }
    if (w < 2){
      u16* dst = (w==0)?Oq:Ok;
      #pragma unroll
      for (int mi=0;mi<4;++mi){
        #pragma unroll
        for (int r=0;r<4;++r){
          int m = m0 + wr*64 + mi*16 + ((lane>>4)<<2) + r;
          int b = m>>10, s = m&1023;
          size_t base0 = ((size_t)b*8192 + (size_t)s)*80;
          #pragma unroll
          for (int ni=0;ni<4;++ni)
            dst[base0 + (size_t)hh4[ni]*81920 + dd4[ni]] = f2bf(acc[mi][ni][r]);
        }
      }
    } else {
      // V^T: [(b*8+h)][d][1024]
      #pragma unroll
      for (int mi=0;mi<4;++mi){
        #pragma unroll
        for (int r=0;r<4;++r){
          int m = m0 + wr*64 + mi*16 + ((lane>>4)<<2) + r;
          int b = m>>10, s = m&1023;
          #pragma unroll
          for (int ni=0;ni<4;++ni)
            Vt[((size_t)(b*8 + hh4[ni])*80 + dd4[ni])*1024 + s] = f2bf(acc[mi][ni][r]);
        }
      }
    }
  } else {
    int nn4[4]; float b4[4];
    #pragma unroll
    for (int ni=0;ni<4;++ni){
      nn4[ni] = n0 + wc*64 + ni*16 + lrow;
      b4[ni] = bias[nn4[ni]];
    }
    #pragma unroll
    for (int mi=0;mi<4;++mi){
      #pragma unroll
      for (int r=0;r<4;++r){
        int m = m0 + wr*64 + mi*16 + ((lane>>4)<<2) + r;
        #pragma unroll
        for (int ni=0;ni<4;++ni)
          Cout[(size_t)m*640 + nn4[ni]] = acc[mi][ni][r] + b4[ni];
      }
    }
  }
}

// ---------------- Flash attention v10 ----------------
// v9's verified inner loop (mi=4, swapped QK^T + sigma-permuted K, streaming
// per-kb softmax, pure-C pack), re-shelled: 128-thread blocks (2 waves x 64 q),
// 768 blocks = exactly 3 blocks/CU (LDS 49.7KB x3 = 149KB), balanced grid.
__global__ __launch_bounds__(128,1) void attn_kernel(
    const u16* __restrict__ Q, const u16* __restrict__ K,
    const u16* __restrict__ Vt, u16* __restrict__ O)
{
  __shared__ u16 Ks[2][64*104];   // sigma-permuted rows, cols 80..95 zeroed
  __shared__ u16 Vs[2][80*72];    // V^T tile [d 80][kv 64 + 8 pad]

  // block remap: XCD-chunked + long-blocks-first (R2/R5-verified, 768 blocks)
  const int bx0 = blockIdx.x;
  const int x = bx0 & 7, o = bx0 >> 3;     // o in [0,96)
  int b, rem;
  if (o < 64){ int idx = x*64 + o;        b = 4 + (idx>>6); rem = idx&63; }
  else       { int idx = x*32 + (o-64);   b = (idx>>6);     rem = idx&63; }
  const int hh = rem>>3, qt = rem&7;
  const int g = b>>2;

  const int tid = threadIdx.x, wid = tid>>6, lane = tid&63;
  const int lrow = lane&15, lk = (lane>>4)<<3;
  const int rbase = (lane>>4)<<2;

  { // zero K pad cols 80..95 in both buffers (128 threads -> 2 passes)
    uint2 z; z.x=0u; z.y=0u;
    #pragma unroll
    for (int i=0;i<2;++i){
      int t = tid + i*128;
      int r = t>>2, c = 80 + ((t&3)<<2);
      *(uint2*)&Ks[0][r*104 + c] = z;
      *(uint2*)&Ks[1][r*104 + c] = z;
    }
  }

  const float SCL = 0.1118033988749895f * 1.4426950408889634f; // 80^-0.5 * log2(e)

  // Q fragments: 4 mi-tiles (64 q/wave), pre-scaled, zero-padded d>=80
  const u16* qbase = Q + ((size_t)((b*8+hh)*1024 + qt*128 + wid*64))*80;
  bf16x8 qf[4][3];
  #pragma unroll
  for (int mi=0;mi<4;++mi){
    #pragma unroll
    for (int kk=0;kk<3;++kk){
      int d0 = kk*32 + lk;
      if (d0 < 80){
        bf16x8 raw = *(const bf16x8*)&qbase[(mi*16+lrow)*80 + d0];
        #pragma unroll
        for (int j=0;j<8;++j) qf[mi][kk][j] = (short)f2bf(bf2f((u16)raw[j])*SCL);
      } else {
        #pragma unroll
        for (int j=0;j<8;++j) qf[mi][kk][j] = 0;
      }
    }
  }

  f32x4 o_acc[4][5];
  float l_r[4];
  #pragma unroll
  for (int mi=0;mi<4;++mi){
    #pragma unroll
    for (int db=0;db<5;++db) o_acc[mi][db] = (f32x4)0.0f;
    l_r[mi] = 0.0f;
  }

  const int nkt = (g==0)?16:64;

  // staging: 640 x 16B chunks each for K (sigma-permuted dest) and V^T.
  // 128 threads x 5 chunks = 640 exactly. (indices compile-time unrolled)
  int kd[5], vd[5], vg[5];
  #pragma unroll
  for (int t=0;t<5;++t){
    int c = tid + 128*t;
    int kv = c/10, dp = c - kv*10;
    int kb = ((kv>>4)&2)|((kv>>2)&1);
    int ii = ((kv>>1)&0xC)|(kv&3);
    kd[t] = (kb*16+ii)*104 + dp*8;
    vd[t] = (c>>3)*72 + ((c&7)<<3);
    vg[t] = (c>>3)*1024 + ((c&7)<<3);
  }

  uint4 kreg[5], vreg[5];

  #define KVBASE(kt, Kb, Vb) { \
    int fk = (g==0)? (b&3) : ((kt)>>4); \
    int s0 = ((g==0)? (kt) : ((kt)&15))<<6; \
    int bk = g*4 + fk; \
    Kb = K  + ((size_t)((bk*8+hh)*1024 + s0))*80; \
    Vb = Vt + ((size_t)(bk*8+hh))*81920 + s0; }

  #define LOADKV(Kb, Vb) { \
    _Pragma("unroll") \
    for (int t=0;t<5;++t){ \
      kreg[t] = *(const uint4*)((Kb) + (tid + 128*t)*8); \
      vreg[t] = *(const uint4*)((Vb) + vg[t]); } }

  #define WRITEKV(buf) { \
    _Pragma("unroll") \
    for (int t=0;t<5;++t){ \
      *(uint4*)&Ks[buf][kd[t]] = kreg[t]; \
      *(uint4*)&Vs[buf][vd[t]] = vreg[t]; } }

  { const u16 *Kb; const u16 *Vb; KVBASE(0, Kb, Vb); LOADKV(Kb, Vb); WRITEKV(0); }
  __syncthreads();

  for (int kt=0; kt<nkt; ++kt){
    const int cur = kt&1;
    const bool more = (kt+1 < nkt);
    if (more){ const u16 *Kb; const u16 *Vb; KVBASE(kt+1, Kb, Vb); LOADKV(Kb, Vb); }

    // V fragments upfront (shared by all mi)
    bf16x8 vfr[2][5];
    #pragma unroll
    for (int kk=0;kk<2;++kk)
      #pragma unroll
      for (int db=0;db<5;++db)
        vfr[kk][db] = *(const bf16x8*)&Vs[cur][(db*16+lrow)*72 + kk*32 + lk];

    // QK^T streamed per kb (16 kv-rows at a time) + softmax + pure-C pack.
    // q = mi*16+(lane&15); kv = (kb>>1)*32 + (lane>>4)*8 + (kb&1)*4 + r
    uint32_t paw[4][2][4];
    #pragma unroll
    for (int kb=0;kb<4;++kb){
      bf16x8 kf0 = *(const bf16x8*)&Ks[cur][(kb*16+lrow)*104 +  0 + lk];
      bf16x8 kf1 = *(const bf16x8*)&Ks[cur][(kb*16+lrow)*104 + 32 + lk];
      bf16x8 kf2 = *(const bf16x8*)&Ks[cur][(kb*16+lrow)*104 + 64 + lk];
      f32x4 s4[4];
      #pragma unroll
      for (int mi=0;mi<4;++mi) s4[mi] = (f32x4)0.0f;
      #pragma unroll
      for (int mi=0;mi<4;++mi){
        s4[mi] = MFMA16(kf0, qf[mi][0], s4[mi]);
        s4[mi] = MFMA16(kf1, qf[mi][1], s4[mi]);
        s4[mi] = MFMA16(kf2, qf[mi][2], s4[mi]);
      }
      #pragma unroll
      for (int mi=0;mi<4;++mi){
        float e0 = __builtin_amdgcn_exp2f(s4[mi][0]);
        float e1 = __builtin_amdgcn_exp2f(s4[mi][1]);
        float e2 = __builtin_amdgcn_exp2f(s4[mi][2]);
        float e3 = __builtin_amdgcn_exp2f(s4[mi][3]);
        l_r[mi] += (e0+e1) + (e2+e3);
        paw[mi][kb>>1][(kb&1)*2    ] = pack_bf16(e0, e1);
        paw[mi][kb>>1][(kb&1)*2 + 1] = pack_bf16(e2, e3);
      }
    }

    // PV
    #pragma unroll
    for (int mi=0;mi<4;++mi)
      #pragma unroll
      for (int kk=0;kk<2;++kk){
        u32x4 w; w.x = paw[mi][kk][0]; w.y = paw[mi][kk][1];
                 w.z = paw[mi][kk][2]; w.w = paw[mi][kk][3];
        bf16x8 pa = __builtin_bit_cast(bf16x8, w);
        #pragma unroll
        for (int db=0;db<5;++db)
          o_acc[mi][db] = MFMA16(pa, vfr[kk][db], o_acc[mi][db]);
      }

    if (more){
      WRITEKV(cur^1);
      __syncthreads();
    }
  }

  // epilogue: reduce l across lane groups (lane&15 = q), redistribute, store
  #pragma unroll
  for (int mi=0;mi<4;++mi){
    float lf = l_r[mi];
    lf += __shfl_xor(lf, 16, 64);
    lf += __shfl_xor(lf, 32, 64);   // full sum for q = mi*16 + (lane&15), replicated
    #pragma unroll
    for (int r=0;r<4;++r){
      float inv = 1.0f / __shfl(lf, (lane & 48) | (rbase + r), 64);
      int s = qt*128 + wid*64 + mi*16 + rbase + r;
      u16* orow = O + ((size_t)(b*1024 + s))*640 + hh*80;
      #pragma unroll
      for (int db=0;db<5;++db)
        orow[db*16 + lrow] = f2bf(o_acc[mi][db][r]*inv);
    }
  }
  #undef KVBASE
  #undef LOADKV
  #undef WRITEKV
}

// ---------------- launch ----------------
extern "C" void kernel_launch(void* const* d_in, const int* in_sizes, int n_in,
                              void* d_out, int out_size, void* d_ws, size_t ws_size,
                              hipStream_t stream)
{
  const float* x  = (const float*)d_in[0];
  const float* Wq = (const float*)d_in[1];
  const float* Wk = (const float*)d_in[2];
  const float* Wv = (const float*)d_in[3];
  const float* Wo = (const float*)d_in[4];
  const float* bo = (const float*)d_in[5];
  float* out = (float*)d_out;

  char* ws = (char*)d_ws;
  u16* xbf = (u16*)(ws);
  u16* wt  = (u16*)(ws + 15728640);
  u16* wot = (u16*)(ws + 18186240);
  u16* Qw  = (u16*)(ws + 19005440);
  u16* Kw  = (u16*)(ws + 34734080);
  u16* Vtw = (u16*)(ws + 50462720);
  u16* Ow  = (u16*)(ws + 66191360);

  cvt_x_kernel<<<7680, 256, 0, stream>>>(x, xbf);
  cvt_w_kernel<<<dim3(20,20,4), dim3(32,8,1), 0, stream>>>(Wq,Wk,Wv,Wo, wt, wot);
  gemm_kernel<0><<<dim3(5,96,3), 256, 0, stream>>>(xbf, wt, nullptr, Qw, Kw, Vtw, nullptr);
  attn_kernel<<<768, 128, 0, stream>>>(Qw, Kw, Vtw, Ow);
  gemm_kernel<1><<<dim3(5,96,1), 256, 0, stream>>>(Ow, wot, bo, nullptr, nullptr, nullptr, out);
}

// Round 12
// 364.784 us; speedup vs baseline: 1.0040x; 1.0040x over previous
//
#include <hip/hip_runtime.h>
#include <stdint.h>

typedef unsigned short u16;
typedef __attribute__((ext_vector_type(8))) short bf16x8;
typedef __attribute__((ext_vector_type(4))) float f32x4;
typedef __attribute__((ext_vector_type(4))) uint32_t u32x4;

#define MFMA16(a,b,c) __builtin_amdgcn_mfma_f32_16x16x32_bf16(a,b,c,0,0,0)

__device__ __forceinline__ float bf2f(u16 u){
  union { float f; uint32_t i; } c; c.i = ((uint32_t)u)<<16; return c.f;
}
__device__ __forceinline__ u16 f2bf(float f){
  union { float f; uint32_t i; } c; c.f = f;
  uint32_t r = c.i + 0x7FFFu + ((c.i>>16)&1u);
  return (u16)(r>>16);
}
// pure-C packed bf16 pair (RNE) — asm v_cvt_pk miscompiles at high reg pressure (R10)
__device__ __forceinline__ uint32_t pack_bf16(float a, float b){
  return (uint32_t)f2bf(a) | ((uint32_t)f2bf(b)<<16);
}

// ---------------- convert x (fp32 -> bf16) ----------------
__global__ void cvt_x_kernel(const float* __restrict__ x, u16* __restrict__ xbf){
  int i = blockIdx.x*256 + threadIdx.x;
  float4 v = ((const float4* __restrict__)x)[i];
  uint2 pk;
  pk.x = (uint32_t)f2bf(v.x) | ((uint32_t)f2bf(v.y)<<16);
  pk.y = (uint32_t)f2bf(v.z) | ((uint32_t)f2bf(v.w)<<16);
  ((uint2*)xbf)[i] = pk;
}

// ------------- transpose + convert weights: W[k][n] -> Wt[n][k] bf16 -------------
__global__ void cvt_w_kernel(const float* __restrict__ Wq, const float* __restrict__ Wk,
                             const float* __restrict__ Wv, const float* __restrict__ Wo,
                             u16* __restrict__ wt, u16* __restrict__ wot){
  __shared__ float t[32][33];
  int w = blockIdx.z;
  const float* W = (w==0)?Wq:(w==1)?Wk:(w==2)?Wv:Wo;
  u16* dst = (w<3) ? (wt + (size_t)w*640*640) : wot;
  int k0 = blockIdx.x*32, n0 = blockIdx.y*32;
  int tx = threadIdx.x, ty = threadIdx.y;
  for (int j=ty; j<32; j+=8) t[j][tx] = W[(size_t)(k0+j)*640 + n0+tx];
  __syncthreads();
  for (int j=ty; j<32; j+=8) dst[(size_t)(n0+j)*640 + k0+tx] = f2bf(t[tx][j]);
}

// ---------------- GEMM: C[12288x640] = A[12288x640] * Bt^T, bf16 MFMA ----------------
template<int MODE>
__global__ __launch_bounds__(256,2) void gemm_kernel(
    const u16* __restrict__ A, const u16* __restrict__ Bt,
    const float* __restrict__ bias,
    u16* __restrict__ Oq, u16* __restrict__ Ok, u16* __restrict__ Vt,
    float* __restrict__ Cout)
{
  __shared__ u16 As[128*64];
  __shared__ u16 Bs[128*64];
  const int n0 = blockIdx.x*128;
  const int m0 = blockIdx.y*128;
  const int w  = blockIdx.z;
  const u16* Bw = Bt + (size_t)w*640*640;
  const int tid = threadIdx.x;
  const int wid = tid>>6, lane = tid&63;
  const int wr = wid>>1, wc = wid&1;
  const int lrow = lane&15, lk = (lane>>4)<<3;

  f32x4 acc[4][4];
  #pragma unroll
  for (int i=0;i<4;++i)
    #pragma unroll
    for (int j=0;j<4;++j) acc[i][j] = (f32x4)0.0f;

  const int srow = wid*32 + (lane>>3);
  const int schunk = (lane&7)*8;

  for (int kt=0; kt<10; ++kt){
    const int k0 = kt*64;
    __syncthreads();
    #pragma unroll
    for (int j=0;j<4;++j){
      const u16* gA = A  + (size_t)(m0 + srow + j*8)*640 + k0 + schunk;
      const u16* gB = Bw + (size_t)(n0 + srow + j*8)*640 + k0 + schunk;
      __builtin_amdgcn_global_load_lds((const __attribute__((address_space(1))) void*)gA,
          (__attribute__((address_space(3))) void*)(As + (wid*32 + j*8)*64), 16, 0, 0);
      __builtin_amdgcn_global_load_lds((const __attribute__((address_space(1))) void*)gB,
          (__attribute__((address_space(3))) void*)(Bs + (wid*32 + j*8)*64), 16, 0, 0);
    }
    __syncthreads();
    #pragma unroll
    for (int kk=0; kk<2; ++kk){
      bf16x8 af[4], bfr[4];
      #pragma unroll
      for (int mi=0;mi<4;++mi)
        af[mi] = *(const bf16x8*)(As + (wr*64 + mi*16 + lrow)*64 + kk*32 + lk);
      #pragma unroll
      for (int ni=0;ni<4;++ni)
        bfr[ni] = *(const bf16x8*)(Bs + (wc*64 + ni*16 + lrow)*64 + kk*32 + lk);
      #pragma unroll
      for (int mi=0;mi<4;++mi)
        #pragma unroll
        for (int ni=0;ni<4;++ni)
          acc[mi][ni] = MFMA16(af[mi], bfr[ni], acc[mi][ni]);
    }
  }

  if (MODE==0){
    int hh4[4], dd4[4];
    #pragma unroll
    for (int ni=0;ni<4;++ni){
      int nn = n0 + wc*64 + ni*16 + lrow;
      hh4[ni] = nn/80; dd4[ni] = nn - hh4[ni]*80;
    }
    if (w < 2){
      u16* dst = (w==0)?Oq:Ok;
      #pragma unroll
      for (int mi=0;mi<4;++mi){
        #pragma unroll
        for (int r=0;r<4;++r){
          int m = m0 + wr*64 + mi*16 + ((lane>>4)<<2) + r;
          int b = m>>10, s = m&1023;
          size_t base0 = ((size_t)b*8192 + (size_t)s)*80;
          #pragma unroll
          for (int ni=0;ni<4;++ni)
            dst[base0 + (size_t)hh4[ni]*81920 + dd4[ni]] = f2bf(acc[mi][ni][r]);
        }
      }
    } else {
      // V^T: [(b*8+h)][d][1024]
      #pragma unroll
      for (int mi=0;mi<4;++mi){
        #pragma unroll
        for (int r=0;r<4;++r){
          int m = m0 + wr*64 + mi*16 + ((lane>>4)<<2) + r;
          int b = m>>10, s = m&1023;
          #pragma unroll
          for (int ni=0;ni<4;++ni)
            Vt[((size_t)(b*8 + hh4[ni])*80 + dd4[ni])*1024 + s] = f2bf(acc[mi][ni][r]);
        }
      }
    }
  } else {
    int nn4[4]; float b4[4];
    #pragma unroll
    for (int ni=0;ni<4;++ni){
      nn4[ni] = n0 + wc*64 + ni*16 + lrow;
      b4[ni] = bias[nn4[ni]];
    }
    #pragma unroll
    for (int mi=0;mi<4;++mi){
      #pragma unroll
      for (int r=0;r<4;++r){
        int m = m0 + wr*64 + mi*16 + ((lane>>4)<<2) + r;
        #pragma unroll
        for (int ni=0;ni<4;++ni)
          Cout[(size_t)m*640 + nn4[ni]] = acc[mi][ni][r] + b4[ni];
      }
    }
  }
}

// ---------------- Flash attention v11: NO-LDS ----------------
// 768 blocks x 256 thr (4 waves x 32 q, mi=2). All operands loaded directly
// from global (L1/L2-resident tiles): K fragments via the sigma-inverse address
// map (values per lane bit-identical to v8's LDS path), V^T fragments direct.
// No __shared__, no barriers, no staging. Swapped QK^T + in-register P.
__global__ __launch_bounds__(256,2) void attn_kernel(
    const u16* __restrict__ Q, const u16* __restrict__ K,
    const u16* __restrict__ Vt, u16* __restrict__ O)
{
  // block remap: XCD-chunked + long-blocks-first (verified)
  const int bx0 = blockIdx.x;
  const int x = bx0 & 7, o = bx0 >> 3;     // o in [0,96)
  int b, rem;
  if (o < 64){ int idx = x*64 + o;        b = 4 + (idx>>6); rem = idx&63; }
  else       { int idx = x*32 + (o-64);   b = (idx>>6);     rem = idx&63; }
  const int hh = rem>>3, qt = rem&7;
  const int g = b>>2;

  const int tid = threadIdx.x, wid = tid>>6, lane = tid&63;
  const int lrow = lane&15, lk = (lane>>4)<<3;
  const int rbase = (lane>>4)<<2;

  // sigma-inverse K row for this lane: kv(kb) = kvbase + (kb&1)*4 + (kb&2)*16
  const int kvbase = ((lrow&12)<<1) | (lrow&3);

  const float SCL = 0.1118033988749895f * 1.4426950408889634f; // 80^-0.5 * log2(e)

  // Q fragments (pre-scaled, zero-padded d>=80). MFMA B-operand (col = q).
  const u16* qbase = Q + ((size_t)((b*8+hh)*1024 + qt*128 + wid*32))*80;
  bf16x8 qf[2][3];
  #pragma unroll
  for (int mi=0;mi<2;++mi){
    #pragma unroll
    for (int kk=0;kk<3;++kk){
      int d0 = kk*32 + lk;
      if (d0 < 80){
        bf16x8 raw = *(const bf16x8*)&qbase[(mi*16+lrow)*80 + d0];
        #pragma unroll
        for (int j=0;j<8;++j) qf[mi][kk][j] = (short)f2bf(bf2f((u16)raw[j])*SCL);
      } else {
        #pragma unroll
        for (int j=0;j<8;++j) qf[mi][kk][j] = 0;
      }
    }
  }

  f32x4 o_acc[2][5];
  float l_r[2];
  #pragma unroll
  for (int mi=0;mi<2;++mi){
    #pragma unroll
    for (int db=0;db<5;++db) o_acc[mi][db] = (f32x4)0.0f;
    l_r[mi] = 0.0f;
  }

  const int nkt = (g==0)?16:64;

  for (int kt=0; kt<nkt; ++kt){
    int fk = (g==0)? (b&3) : (kt>>4);
    int s0 = ((g==0)? kt : (kt&15))<<6;
    int bk = g*4 + fk;
    const u16* Kb  = K  + ((size_t)((bk*8+hh)*1024 + s0))*80;
    const u16* VbT = Vt + ((size_t)(bk*8+hh))*81920 + s0;

    // V fragments direct from global (L1/L2) — issued early, consumed in PV
    bf16x8 vfr[2][5];
    #pragma unroll
    for (int kk=0;kk<2;++kk)
      #pragma unroll
      for (int db=0;db<5;++db)
        vfr[kk][db] = *(const bf16x8*)&VbT[(size_t)(db*16+lrow)*1024 + kk*32 + lk];

    // S^T = mfma(K,Q): K fragments direct from global via sigma-inverse rows.
    // lane holds q = mi*16+lrow; kv = (kb>>1)*32 + (lane>>4)*8 + (kb&1)*4 + r
    f32x4 st[2][4];
    #pragma unroll
    for (int mi=0;mi<2;++mi)
      #pragma unroll
      for (int kb=0;kb<4;++kb) st[mi][kb] = (f32x4)0.0f;
    #pragma unroll
    for (int kk=0;kk<3;++kk){
      const int d0 = kk*32 + lk;
      bf16x8 kf[4];
      #pragma unroll
      for (int kb=0;kb<4;++kb){
        if (d0 < 80){
          int kvrow = kvbase + (kb&1)*4 + ((kb&2)<<4);
          kf[kb] = *(const bf16x8*)&Kb[(size_t)kvrow*80 + d0];
        } else {
          #pragma unroll
          for (int j=0;j<8;++j) kf[kb][j] = 0;
        }
      }
      __builtin_amdgcn_s_setprio(1);
      #pragma unroll
      for (int mi=0;mi<2;++mi)
        #pragma unroll
        for (int kb=0;kb<4;++kb)
          st[mi][kb] = MFMA16(kf[kb], qf[mi][kk], st[mi][kb]);
      __builtin_amdgcn_s_setprio(0);
    }

    // softmax (no max-tracking; logits bounded) + in-register pack (pure C)
    bf16x8 pa[2][2];
    #pragma unroll
    for (int mi=0;mi<2;++mi){
      #pragma unroll
      for (int kb=0;kb<4;++kb)
        #pragma unroll
        for (int r=0;r<4;++r)
          st[mi][kb][r] = __builtin_amdgcn_exp2f(st[mi][kb][r]);
      float s0s = (st[mi][0][0]+st[mi][0][1]) + (st[mi][0][2]+st[mi][0][3]);
      float s1s = (st[mi][1][0]+st[mi][1][1]) + (st[mi][1][2]+st[mi][1][3]);
      float s2s = (st[mi][2][0]+st[mi][2][1]) + (st[mi][2][2]+st[mi][2][3]);
      float s3s = (st[mi][3][0]+st[mi][3][1]) + (st[mi][3][2]+st[mi][3][3]);
      l_r[mi] += (s0s+s1s) + (s2s+s3s);
      #pragma unroll
      for (int kk=0;kk<2;++kk){
        u32x4 w;
        w.x = pack_bf16(st[mi][2*kk  ][0], st[mi][2*kk  ][1]);
        w.y = pack_bf16(st[mi][2*kk  ][2], st[mi][2*kk  ][3]);
        w.z = pack_bf16(st[mi][2*kk+1][0], st[mi][2*kk+1][1]);
        w.w = pack_bf16(st[mi][2*kk+1][2], st[mi][2*kk+1][3]);
        pa[mi][kk] = __builtin_bit_cast(bf16x8, w);
      }
    }

    // PV
    __builtin_amdgcn_s_setprio(1);
    #pragma unroll
    for (int mi=0;mi<2;++mi)
      #pragma unroll
      for (int kk=0;kk<2;++kk)
        #pragma unroll
        for (int db=0;db<5;++db)
          o_acc[mi][db] = MFMA16(pa[mi][kk], vfr[kk][db], o_acc[mi][db]);
    __builtin_amdgcn_s_setprio(0);
  }

  // epilogue: reduce l across lane groups (lane&15 = q), redistribute, store
  #pragma unroll
  for (int mi=0;mi<2;++mi){
    float lf = l_r[mi];
    lf += __shfl_xor(lf, 16, 64);
    lf += __shfl_xor(lf, 32, 64);   // full sum for q = mi*16 + lrow, replicated
    #pragma unroll
    for (int r=0;r<4;++r){
      float inv = 1.0f / __shfl(lf, (lane & 48) | (rbase + r), 64);
      int s = qt*128 + wid*32 + mi*16 + rbase + r;
      u16* orow = O + ((size_t)(b*1024 + s))*640 + hh*80;
      #pragma unroll
      for (int db=0;db<5;++db)
        orow[db*16 + lrow] = f2bf(o_acc[mi][db][r]*inv);
    }
  }
}

// ---------------- launch ----------------
extern "C" void kernel_launch(void* const* d_in, const int* in_sizes, int n_in,
                              void* d_out, int out_size, void* d_ws, size_t ws_size,
                              hipStream_t stream)
{
  const float* x  = (const float*)d_in[0];
  const float* Wq = (const float*)d_in[1];
  const float* Wk = (const float*)d_in[2];
  const float* Wv = (const float*)d_in[3];
  const float* Wo = (const float*)d_in[4];
  const float* bo = (const float*)d_in[5];
  float* out = (float*)d_out;

  char* ws = (char*)d_ws;
  u16* xbf = (u16*)(ws);
  u16* wt  = (u16*)(ws + 15728640);
  u16* wot = (u16*)(ws + 18186240);
  u16* Qw  = (u16*)(ws + 19005440);
  u16* Kw  = (u16*)(ws + 34734080);
  u16* Vtw = (u16*)(ws + 50462720);
  u16* Ow  = (u16*)(ws + 66191360);

  cvt_x_kernel<<<7680, 256, 0, stream>>>(x, xbf);
  cvt_w_kernel<<<dim3(20,20,4), dim3(32,8,1), 0, stream>>>(Wq,Wk,Wv,Wo, wt, wot);
  gemm_kernel<0><<<dim3(5,96,3), 256, 0, stream>>>(xbf, wt, nullptr, Qw, Kw, Vtw, nullptr);
  attn_kernel<<<768, 256, 0, stream>>>(Qw, Kw, Vtw, Ow);
  gemm_kernel<1><<<dim3(5,96,1), 256, 0, stream>>>(Ow, wot, bo, nullptr, nullptr, nullptr, out);
}

// Round 13
// 364.517 us; speedup vs baseline: 1.0047x; 1.0007x over previous
//
#include <hip/hip_runtime.h>
#include <stdint.h>

typedef unsigned short u16;
typedef __attribute__((ext_vector_type(8))) short bf16x8;
typedef __attribute__((ext_vector_type(4))) float f32x4;
typedef __attribute__((ext_vector_type(4))) uint32_t u32x4;

#define MFMA16(a,b,c) __builtin_amdgcn_mfma_f32_16x16x32_bf16(a,b,c,0,0,0)

__device__ __forceinline__ float bf2f(u16 u){
  union { float f; uint32_t i; } c; c.i = ((uint32_t)u)<<16; return c.f;
}
__device__ __forceinline__ u16 f2bf(float f){
  union { float f; uint32_t i; } c; c.f = f;
  uint32_t r = c.i + 0x7FFFu + ((c.i>>16)&1u);
  return (u16)(r>>16);
}
// pure-C packed bf16 pair (RNE) — asm v_cvt_pk miscompiles at high reg pressure (R10)
__device__ __forceinline__ uint32_t pack_bf16(float a, float b){
  return (uint32_t)f2bf(a) | ((uint32_t)f2bf(b)<<16);
}

// ---------------- convert x (fp32 -> bf16) ----------------
__global__ void cvt_x_kernel(const float* __restrict__ x, u16* __restrict__ xbf){
  int i = blockIdx.x*256 + threadIdx.x;
  float4 v = ((const float4* __restrict__)x)[i];
  uint2 pk;
  pk.x = (uint32_t)f2bf(v.x) | ((uint32_t)f2bf(v.y)<<16);
  pk.y = (uint32_t)f2bf(v.z) | ((uint32_t)f2bf(v.w)<<16);
  ((uint2*)xbf)[i] = pk;
}

// ------------- transpose + convert weights: W[k][n] -> Wt[n][k] bf16 -------------
__global__ void cvt_w_kernel(const float* __restrict__ Wq, const float* __restrict__ Wk,
                             const float* __restrict__ Wv, const float* __restrict__ Wo,
                             u16* __restrict__ wt, u16* __restrict__ wot){
  __shared__ float t[32][33];
  int w = blockIdx.z;
  const float* W = (w==0)?Wq:(w==1)?Wk:(w==2)?Wv:Wo;
  u16* dst = (w<3) ? (wt + (size_t)w*640*640) : wot;
  int k0 = blockIdx.x*32, n0 = blockIdx.y*32;
  int tx = threadIdx.x, ty = threadIdx.y;
  for (int j=ty; j<32; j+=8) t[j][tx] = W[(size_t)(k0+j)*640 + n0+tx];
  __syncthreads();
  for (int j=ty; j<32; j+=8) dst[(size_t)(n0+j)*640 + k0+tx] = f2bf(t[tx][j]);
}

// ---------------- GEMM: C[12288x640] = A[12288x640] * Bt^T, bf16 MFMA ----------------
template<int MODE>
__global__ __launch_bounds__(256,2) void gemm_kernel(
    const u16* __restrict__ A, const u16* __restrict__ Bt,
    const float* __restrict__ bias,
    u16* __restrict__ Oq, u16* __restrict__ Ok, u16* __restrict__ Vt,
    float* __restrict__ Cout)
{
  __shared__ u16 As[128*64];
  __shared__ u16 Bs[128*64];
  const int n0 = blockIdx.x*128;
  const int m0 = blockIdx.y*128;
  const int w  = blockIdx.z;
  const u16* Bw = Bt + (size_t)w*640*640;
  const int tid = threadIdx.x;
  const int wid = tid>>6, lane = tid&63;
  const int wr = wid>>1, wc = wid&1;
  const int lrow = lane&15, lk = (lane>>4)<<3;

  f32x4 acc[4][4];
  #pragma unroll
  for (int i=0;i<4;++i)
    #pragma unroll
    for (int j=0;j<4;++j) acc[i][j] = (f32x4)0.0f;

  const int srow = wid*32 + (lane>>3);
  const int schunk = (lane&7)*8;

  for (int kt=0; kt<10; ++kt){
    const int k0 = kt*64;
    __syncthreads();
    #pragma unroll
    for (int j=0;j<4;++j){
      const u16* gA = A  + (size_t)(m0 + srow + j*8)*640 + k0 + schunk;
      const u16* gB = Bw + (size_t)(n0 + srow + j*8)*640 + k0 + schunk;
      __builtin_amdgcn_global_load_lds((const __attribute__((address_space(1))) void*)gA,
          (__attribute__((address_space(3))) void*)(As + (wid*32 + j*8)*64), 16, 0, 0);
      __builtin_amdgcn_global_load_lds((const __attribute__((address_space(1))) void*)gB,
          (__attribute__((address_space(3))) void*)(Bs + (wid*32 + j*8)*64), 16, 0, 0);
    }
    __syncthreads();
    #pragma unroll
    for (int kk=0; kk<2; ++kk){
      bf16x8 af[4], bfr[4];
      #pragma unroll
      for (int mi=0;mi<4;++mi)
        af[mi] = *(const bf16x8*)(As + (wr*64 + mi*16 + lrow)*64 + kk*32 + lk);
      #pragma unroll
      for (int ni=0;ni<4;++ni)
        bfr[ni] = *(const bf16x8*)(Bs + (wc*64 + ni*16 + lrow)*64 + kk*32 + lk);
      #pragma unroll
      for (int mi=0;mi<4;++mi)
        #pragma unroll
        for (int ni=0;ni<4;++ni)
          acc[mi][ni] = MFMA16(af[mi], bfr[ni], acc[mi][ni]);
    }
  }

  if (MODE==0){
    int hh4[4], dd4[4];
    #pragma unroll
    for (int ni=0;ni<4;++ni){
      int nn = n0 + wc*64 + ni*16 + lrow;
      hh4[ni] = nn/80; dd4[ni] = nn - hh4[ni]*80;
    }
    if (w < 2){
      u16* dst = (w==0)?Oq:Ok;
      #pragma unroll
      for (int mi=0;mi<4;++mi){
        #pragma unroll
        for (int r=0;r<4;++r){
          int m = m0 + wr*64 + mi*16 + ((lane>>4)<<2) + r;
          int b = m>>10, s = m&1023;
          size_t base0 = ((size_t)b*8192 + (size_t)s)*80;
          #pragma unroll
          for (int ni=0;ni<4;++ni)
            dst[base0 + (size_t)hh4[ni]*81920 + dd4[ni]] = f2bf(acc[mi][ni][r]);
        }
      }
    } else {
      // V^T: [(b*8+h)][d][1024]
      #pragma unroll
      for (int mi=0;mi<4;++mi){
        #pragma unroll
        for (int r=0;r<4;++r){
          int m = m0 + wr*64 + mi*16 + ((lane>>4)<<2) + r;
          int b = m>>10, s = m&1023;
          #pragma unroll
          for (int ni=0;ni<4;++ni)
            Vt[((size_t)(b*8 + hh4[ni])*80 + dd4[ni])*1024 + s] = f2bf(acc[mi][ni][r]);
        }
      }
    }
  } else {
    int nn4[4]; float b4[4];
    #pragma unroll
    for (int ni=0;ni<4;++ni){
      nn4[ni] = n0 + wc*64 + ni*16 + lrow;
      b4[ni] = bias[nn4[ni]];
    }
    #pragma unroll
    for (int mi=0;mi<4;++mi){
      #pragma unroll
      for (int r=0;r<4;++r){
        int m = m0 + wr*64 + mi*16 + ((lane>>4)<<2) + r;
        #pragma unroll
        for (int ni=0;ni<4;++ni)
          Cout[(size_t)m*640 + nn4[ni]] = acc[mi][ni][r] + b4[ni];
      }
    }
  }
}

// ---------------- Flash attention v11: NO-LDS ----------------
// 768 blocks x 256 thr (4 waves x 32 q, mi=2). All operands loaded directly
// from global (L1/L2-resident tiles): K fragments via the sigma-inverse address
// map (values per lane bit-identical to v8's LDS path), V^T fragments direct.
// No __shared__, no barriers, no staging. Swapped QK^T + in-register P.
__global__ __launch_bounds__(256,2) void attn_kernel(
    const u16* __restrict__ Q, const u16* __restrict__ K,
    const u16* __restrict__ Vt, u16* __restrict__ O)
{
  // block remap: XCD-chunked + long-blocks-first (verified)
  const int bx0 = blockIdx.x;
  const int x = bx0 & 7, o = bx0 >> 3;     // o in [0,96)
  int b, rem;
  if (o < 64){ int idx = x*64 + o;        b = 4 + (idx>>6); rem = idx&63; }
  else       { int idx = x*32 + (o-64);   b = (idx>>6);     rem = idx&63; }
  const int hh = rem>>3, qt = rem&7;
  const int g = b>>2;

  const int tid = threadIdx.x, wid = tid>>6, lane = tid&63;
  const int lrow = lane&15, lk = (lane>>4)<<3;
  const int rbase = (lane>>4)<<2;

  // sigma-inverse K row for this lane: kv(kb) = kvbase + (kb&1)*4 + (kb&2)*16
  const int kvbase = ((lrow&12)<<1) | (lrow&3);

  const float SCL = 0.1118033988749895f * 1.4426950408889634f; // 80^-0.5 * log2(e)

  // Q fragments (pre-scaled, zero-padded d>=80). MFMA B-operand (col = q).
  const u16* qbase = Q + ((size_t)((b*8+hh)*1024 + qt*128 + wid*32))*80;
  bf16x8 qf[2][3];
  #pragma unroll
  for (int mi=0;mi<2;++mi){
    #pragma unroll
    for (int kk=0;kk<3;++kk){
      int d0 = kk*32 + lk;
      if (d0 < 80){
        bf16x8 raw = *(const bf16x8*)&qbase[(mi*16+lrow)*80 + d0];
        #pragma unroll
        for (int j=0;j<8;++j) qf[mi][kk][j] = (short)f2bf(bf2f((u16)raw[j])*SCL);
      } else {
        #pragma unroll
        for (int j=0;j<8;++j) qf[mi][kk][j] = 0;
      }
    }
  }

  f32x4 o_acc[2][5];
  float l_r[2];
  #pragma unroll
  for (int mi=0;mi<2;++mi){
    #pragma unroll
    for (int db=0;db<5;++db) o_acc[mi][db] = (f32x4)0.0f;
    l_r[mi] = 0.0f;
  }

  const int nkt = (g==0)?16:64;

  for (int kt=0; kt<nkt; ++kt){
    int fk = (g==0)? (b&3) : (kt>>4);
    int s0 = ((g==0)? kt : (kt&15))<<6;
    int bk = g*4 + fk;
    const u16* Kb  = K  + ((size_t)((bk*8+hh)*1024 + s0))*80;
    const u16* VbT = Vt + ((size_t)(bk*8+hh))*81920 + s0;

    // V fragments direct from global (L1/L2) — issued early, consumed in PV
    bf16x8 vfr[2][5];
    #pragma unroll
    for (int kk=0;kk<2;++kk)
      #pragma unroll
      for (int db=0;db<5;++db)
        vfr[kk][db] = *(const bf16x8*)&VbT[(size_t)(db*16+lrow)*1024 + kk*32 + lk];

    // S^T = mfma(K,Q): K fragments direct from global via sigma-inverse rows.
    // lane holds q = mi*16+lrow; kv = (kb>>1)*32 + (lane>>4)*8 + (kb&1)*4 + r
    f32x4 st[2][4];
    #pragma unroll
    for (int mi=0;mi<2;++mi)
      #pragma unroll
      for (int kb=0;kb<4;++kb) st[mi][kb] = (f32x4)0.0f;
    #pragma unroll
    for (int kk=0;kk<3;++kk){
      const int d0 = kk*32 + lk;
      bf16x8 kf[4];
      #pragma unroll
      for (int kb=0;kb<4;++kb){
        if (d0 < 80){
          int kvrow = kvbase + (kb&1)*4 + ((kb&2)<<4);
          kf[kb] = *(const bf16x8*)&Kb[(size_t)kvrow*80 + d0];
        } else {
          #pragma unroll
          for (int j=0;j<8;++j) kf[kb][j] = 0;
        }
      }
      __builtin_amdgcn_s_setprio(1);
      #pragma unroll
      for (int mi=0;mi<2;++mi)
        #pragma unroll
        for (int kb=0;kb<4;++kb)
          st[mi][kb] = MFMA16(kf[kb], qf[mi][kk], st[mi][kb]);
      __builtin_amdgcn_s_setprio(0);
    }

    // softmax (no max-tracking; logits bounded) + in-register pack (pure C)
    bf16x8 pa[2][2];
    #pragma unroll
    for (int mi=0;mi<2;++mi){
      #pragma unroll
      for (int kb=0;kb<4;++kb)
        #pragma unroll
        for (int r=0;r<4;++r)
          st[mi][kb][r] = __builtin_amdgcn_exp2f(st[mi][kb][r]);
      float s0s = (st[mi][0][0]+st[mi][0][1]) + (st[mi][0][2]+st[mi][0][3]);
      float s1s = (st[mi][1][0]+st[mi][1][1]) + (st[mi][1][2]+st[mi][1][3]);
      float s2s = (st[mi][2][0]+st[mi][2][1]) + (st[mi][2][2]+st[mi][2][3]);
      float s3s = (st[mi][3][0]+st[mi][3][1]) + (st[mi][3][2]+st[mi][3][3]);
      l_r[mi] += (s0s+s1s) + (s2s+s3s);
      #pragma unroll
      for (int kk=0;kk<2;++kk){
        u32x4 w;
        w.x = pack_bf16(st[mi][2*kk  ][0], st[mi][2*kk  ][1]);
        w.y = pack_bf16(st[mi][2*kk  ][2], st[mi][2*kk  ][3]);
        w.z = pack_bf16(st[mi][2*kk+1][0], st[mi][2*kk+1][1]);
        w.w = pack_bf16(st[mi][2*kk+1][2], st[mi][2*kk+1][3]);
        pa[mi][kk] = __builtin_bit_cast(bf16x8, w);
      }
    }

    // PV
    __builtin_amdgcn_s_setprio(1);
    #pragma unroll
    for (int mi=0;mi<2;++mi)
      #pragma unroll
      for (int kk=0;kk<2;++kk)
        #pragma unroll
        for (int db=0;db<5;++db)
          o_acc[mi][db] = MFMA16(pa[mi][kk], vfr[kk][db], o_acc[mi][db]);
    __builtin_amdgcn_s_setprio(0);
  }

  // epilogue: reduce l across lane groups (lane&15 = q), redistribute, store
  #pragma unroll
  for (int mi=0;mi<2;++mi){
    float lf = l_r[mi];
    lf += __shfl_xor(lf, 16, 64);
    lf += __shfl_xor(lf, 32, 64);   // full sum for q = mi*16 + lrow, replicated
    #pragma unroll
    for (int r=0;r<4;++r){
      float inv = 1.0f / __shfl(lf, (lane & 48) | (rbase + r), 64);
      int s = qt*128 + wid*32 + mi*16 + rbase + r;
      u16* orow = O + ((size_t)(b*1024 + s))*640 + hh*80;
      #pragma unroll
      for (int db=0;db<5;++db)
        orow[db*16 + lrow] = f2bf(o_acc[mi][db][r]*inv);
    }
  }
}

// ---------------- launch ----------------
extern "C" void kernel_launch(void* const* d_in, const int* in_sizes, int n_in,
                              void* d_out, int out_size, void* d_ws, size_t ws_size,
                              hipStream_t stream)
{
  const float* x  = (const float*)d_in[0];
  const float* Wq = (const float*)d_in[1];
  const float* Wk = (const float*)d_in[2];
  const float* Wv = (const float*)d_in[3];
  const float* Wo = (const float*)d_in[4];
  const float* bo = (const float*)d_in[5];
  float* out = (float*)d_out;

  char* ws = (char*)d_ws;
  u16* xbf = (u16*)(ws);
  u16* wt  = (u16*)(ws + 15728640);
  u16* wot = (u16*)(ws + 18186240);
  u16* Qw  = (u16*)(ws + 19005440);
  u16* Kw  = (u16*)(ws + 34734080);
  u16* Vtw = (u16*)(ws + 50462720);
  u16* Ow  = (u16*)(ws + 66191360);

  cvt_x_kernel<<<7680, 256, 0, stream>>>(x, xbf);
  cvt_w_kernel<<<dim3(20,20,4), dim3(32,8,1), 0, stream>>>(Wq,Wk,Wv,Wo, wt, wot);
  gemm_kernel<0><<<dim3(5,96,3), 256, 0, stream>>>(xbf, wt, nullptr, Qw, Kw, Vtw, nullptr);
  attn_kernel<<<768, 256, 0, stream>>>(Qw, Kw, Vtw, Ow);
  gemm_kernel<1><<<dim3(5,96,1), 256, 0, stream>>>(Ow, wot, bo, nullptr, nullptr, nullptr, out);
}

// Round 14
// 205.356 us; speedup vs baseline: 1.7834x; 1.7750x over previous
//
#include <hip/hip_runtime.h>
#include <stdint.h>

typedef unsigned short u16;
typedef __attribute__((ext_vector_type(8))) short bf16x8;
typedef __attribute__((ext_vector_type(4))) float f32x4;
typedef __attribute__((ext_vector_type(4))) uint32_t u32x4;

#define MFMA16(a,b,c) __builtin_amdgcn_mfma_f32_16x16x32_bf16(a,b,c,0,0,0)

__device__ __forceinline__ float bf2f(u16 u){
  union { float f; uint32_t i; } c; c.i = ((uint32_t)u)<<16; return c.f;
}
__device__ __forceinline__ u16 f2bf(float f){
  union { float f; uint32_t i; } c; c.f = f;
  uint32_t r = c.i + 0x7FFFu + ((c.i>>16)&1u);
  return (u16)(r>>16);
}
// asm cvt_pk is safe at low reg pressure (R5/R8-verified); banned >150 VGPR (R10)
__device__ __forceinline__ uint32_t cvt_pk_bf16(float a, float b){
  uint32_t r;
  asm("v_cvt_pk_bf16_f32 %0, %1, %2" : "=v"(r) : "v"(a), "v"(b));
  return r;  // lo = bf16(a), hi = bf16(b)
}

#define GLD(gsrc, ldst) __builtin_amdgcn_global_load_lds( \
    (const __attribute__((address_space(1))) void*)(gsrc), \
    (__attribute__((address_space(3))) void*)(ldst), 16, 0, 0)

// ---------------- convert x (fp32 -> bf16) ----------------
__global__ void cvt_x_kernel(const float* __restrict__ x, u16* __restrict__ xbf){
  int i = blockIdx.x*256 + threadIdx.x;
  float4 v = ((const float4* __restrict__)x)[i];
  uint2 pk;
  pk.x = (uint32_t)f2bf(v.x) | ((uint32_t)f2bf(v.y)<<16);
  pk.y = (uint32_t)f2bf(v.z) | ((uint32_t)f2bf(v.w)<<16);
  ((uint2*)xbf)[i] = pk;
}

// ------------- transpose + convert weights: W[k][n] -> Wt[n][k] bf16 -------------
__global__ void cvt_w_kernel(const float* __restrict__ Wq, const float* __restrict__ Wk,
                             const float* __restrict__ Wv, const float* __restrict__ Wo,
                             u16* __restrict__ wt, u16* __restrict__ wot){
  __shared__ float t[32][33];
  int w = blockIdx.z;
  const float* W = (w==0)?Wq:(w==1)?Wk:(w==2)?Wv:Wo;
  u16* dst = (w<3) ? (wt + (size_t)w*640*640) : wot;
  int k0 = blockIdx.x*32, n0 = blockIdx.y*32;
  int tx = threadIdx.x, ty = threadIdx.y;
  for (int j=ty; j<32; j+=8) t[j][tx] = W[(size_t)(k0+j)*640 + n0+tx];
  __syncthreads();
  for (int j=ty; j<32; j+=8) dst[(size_t)(n0+j)*640 + k0+tx] = f2bf(t[tx][j]);
}

// ---------------- GEMM: C[12288x640] = A[12288x640] * Bt^T, bf16 MFMA ----------------
// MODE 0: w=0 -> Q [b][h][s][80]
//         w=1 -> Kg [bh][tile16][sigma-row 64][104] (cols 80..95 zeroed, 96..103 pad)
//         w=2 -> Vg [bh][tile16][d 80][64] with XOR-chunk swizzle baked in
// MODE 1: fp32 out = acc + bias, row-major [m][640]
template<int MODE>
__global__ __launch_bounds__(256,2) void gemm_kernel(
    const u16* __restrict__ A, const u16* __restrict__ Bt,
    const float* __restrict__ bias,
    u16* __restrict__ Oq, u16* __restrict__ Kg, u16* __restrict__ Vg,
    float* __restrict__ Cout)
{
  __shared__ u16 As[128*64];
  __shared__ u16 Bs[128*64];
  const int n0 = blockIdx.x*128;
  const int m0 = blockIdx.y*128;
  const int w  = blockIdx.z;
  const u16* Bw = Bt + (size_t)w*640*640;
  const int tid = threadIdx.x;
  const int wid = tid>>6, lane = tid&63;
  const int wr = wid>>1, wc = wid&1;
  const int lrow = lane&15, lk = (lane>>4)<<3;

  f32x4 acc[4][4];
  #pragma unroll
  for (int i=0;i<4;++i)
    #pragma unroll
    for (int j=0;j<4;++j) acc[i][j] = (f32x4)0.0f;

  const int srow = wid*32 + (lane>>3);
  const int schunk = (lane&7)*8;

  for (int kt=0; kt<10; ++kt){
    const int k0 = kt*64;
    __syncthreads();
    #pragma unroll
    for (int j=0;j<4;++j){
      const u16* gA = A  + (size_t)(m0 + srow + j*8)*640 + k0 + schunk;
      const u16* gB = Bw + (size_t)(n0 + srow + j*8)*640 + k0 + schunk;
      GLD(gA, As + (wid*32 + j*8)*64);
      GLD(gB, Bs + (wid*32 + j*8)*64);
    }
    __syncthreads();
    #pragma unroll
    for (int kk=0; kk<2; ++kk){
      bf16x8 af[4], bfr[4];
      #pragma unroll
      for (int mi=0;mi<4;++mi)
        af[mi] = *(const bf16x8*)(As + (wr*64 + mi*16 + lrow)*64 + kk*32 + lk);
      #pragma unroll
      for (int ni=0;ni<4;++ni)
        bfr[ni] = *(const bf16x8*)(Bs + (wc*64 + ni*16 + lrow)*64 + kk*32 + lk);
      #pragma unroll
      for (int mi=0;mi<4;++mi)
        #pragma unroll
        for (int ni=0;ni<4;++ni)
          acc[mi][ni] = MFMA16(af[mi], bfr[ni], acc[mi][ni]);
    }
  }

  if (MODE==0){
    int hh4[4], dd4[4];
    #pragma unroll
    for (int ni=0;ni<4;++ni){
      int nn = n0 + wc*64 + ni*16 + lrow;
      hh4[ni] = nn/80; dd4[ni] = nn - hh4[ni]*80;
    }
    if (w == 0){
      #pragma unroll
      for (int mi=0;mi<4;++mi){
        #pragma unroll
        for (int r=0;r<4;++r){
          int m = m0 + wr*64 + mi*16 + ((lane>>4)<<2) + r;
          int b = m>>10, s = m&1023;
          size_t base0 = ((size_t)b*8192 + (size_t)s)*80;
          #pragma unroll
          for (int ni=0;ni<4;++ni)
            Oq[base0 + (size_t)hh4[ni]*81920 + dd4[ni]] = f2bf(acc[mi][ni][r]);
        }
      }
    } else if (w == 1){
      // K: sigma-permuted row within each 64-kv tile, 104-col rows, zeros at 80..95
      #pragma unroll
      for (int mi=0;mi<4;++mi){
        #pragma unroll
        for (int r=0;r<4;++r){
          int m = m0 + wr*64 + mi*16 + ((lane>>4)<<2) + r;
          int b = m>>10, s = m&1023;
          int tile = s>>6, kv = s&63;
          int kb = ((kv>>4)&2)|((kv>>2)&1);
          int ii = ((kv>>1)&0xC)|(kv&3);
          int sr = kb*16 + ii;
          #pragma unroll
          for (int ni=0;ni<4;++ni){
            size_t base = ((size_t)((b*8+hh4[ni])*16 + tile))*6656 + sr*104;
            Kg[base + dd4[ni]] = f2bf(acc[mi][ni][r]);
            if (dd4[ni] >= 64) Kg[base + dd4[ni] + 16] = 0;  // zero cols 80..95
          }
        }
      }
    } else {
      // V^T with XOR-chunk swizzle: row d, kv j -> chunk (j>>3)^(d&7)
      #pragma unroll
      for (int mi=0;mi<4;++mi){
        #pragma unroll
        for (int r=0;r<4;++r){
          int m = m0 + wr*64 + mi*16 + ((lane>>4)<<2) + r;
          int b = m>>10, s = m&1023;
          int tile = s>>6, j = s&63;
          #pragma unroll
          for (int ni=0;ni<4;++ni){
            int d = dd4[ni];
            int pos = ((((j>>3) ^ (d&7))<<3)) | (j&7);
            Vg[((size_t)((b*8+hh4[ni])*16 + tile))*5120 + d*64 + pos] = f2bf(acc[mi][ni][r]);
          }
        }
      }
    }
  } else {
    int nn4[4]; float b4[4];
    #pragma unroll
    for (int ni=0;ni<4;++ni){
      nn4[ni] = n0 + wc*64 + ni*16 + lrow;
      b4[ni] = bias[nn4[ni]];
    }
    #pragma unroll
    for (int mi=0;mi<4;++mi){
      #pragma unroll
      for (int r=0;r<4;++r){
        int m = m0 + wr*64 + mi*16 + ((lane>>4)<<2) + r;
        #pragma unroll
        for (int ni=0;ni<4;++ni)
          Cout[(size_t)m*640 + nn4[ni]] = acc[mi][ni][r] + b4[ni];
      }
    }
  }
}

// ---------------- Flash attention v12: DMA-staged ----------------
// v8's verified core (768 blocks, 4 waves x 32 q, mi=2, swapped QK^T, in-register
// cvt_pk P, 1 barrier/tile) with ALL staging via global_load_lds from the
// layout-baked Kg/Vg buffers: zero staging registers, zero ds_writes.
__global__ __launch_bounds__(256,2) void attn_kernel(
    const u16* __restrict__ Q, const u16* __restrict__ Kg,
    const u16* __restrict__ Vg, u16* __restrict__ O)
{
  __shared__ u16 Ks[2][64*104];   // sigma rows; cols 80..95 zero (from Kg), 96..103 pad
  __shared__ u16 Vs[2][80*64];    // XOR-chunk-swizzled V^T tile

  // block remap: XCD-chunked + long-blocks-first (verified)
  const int bx0 = blockIdx.x;
  const int x = bx0 & 7, o = bx0 >> 3;     // o in [0,96)
  int b, rem;
  if (o < 64){ int idx = x*64 + o;        b = 4 + (idx>>6); rem = idx&63; }
  else       { int idx = x*32 + (o-64);   b = (idx>>6);     rem = idx&63; }
  const int hh = rem>>3, qt = rem&7;
  const int g = b>>2;

  const int tid = threadIdx.x, wid = tid>>6, lane = tid&63;
  const int lrow = lane&15, lk = (lane>>4)<<3;
  const int rbase = (lane>>4)<<2;

  const float SCL = 0.1118033988749895f * 1.4426950408889634f; // 80^-0.5 * log2(e)

  // Q fragments (pre-scaled, zero-padded d>=80). MFMA B-operand (col = q).
  const u16* qbase = Q + ((size_t)((b*8+hh)*1024 + qt*128 + wid*32))*80;
  bf16x8 qf[2][3];
  #pragma unroll
  for (int mi=0;mi<2;++mi){
    #pragma unroll
    for (int kk=0;kk<3;++kk){
      int d0 = kk*32 + lk;
      if (d0 < 80){
        bf16x8 raw = *(const bf16x8*)&qbase[(mi*16+lrow)*80 + d0];
        #pragma unroll
        for (int j=0;j<8;++j) qf[mi][kk][j] = (short)f2bf(bf2f((u16)raw[j])*SCL);
      } else {
        #pragma unroll
        for (int j=0;j<8;++j) qf[mi][kk][j] = 0;
      }
    }
  }

  f32x4 o_acc[2][5];
  float l_r[2];
  #pragma unroll
  for (int mi=0;mi<2;++mi){
    #pragma unroll
    for (int db=0;db<5;++db) o_acc[mi][db] = (f32x4)0.0f;
    l_r[mi] = 0.0f;
  }

  const int nkt = (g==0)?16:64;

  // DMA-stage one KV tile: K 832 chunks (3 full calls + wave0 quarter),
  // V 640 chunks (2 full calls + waves 0-1).
  #define ISSUE(buf, kt) { \
    int fk = (g==0)? (b&3) : ((kt)>>4); \
    int tile = (g==0)? (kt) : ((kt)&15); \
    int bk = g*4 + fk; \
    const u16* Kb = Kg + ((size_t)((bk*8+hh)*16 + tile))*6656; \
    const u16* Vb = Vg + ((size_t)((bk*8+hh)*16 + tile))*5120; \
    _Pragma("unroll") \
    for (int c=0;c<3;++c) \
      GLD(Kb + (c*256+tid)*8, &Ks[buf][0] + (c*256+wid*64)*8); \
    if (wid==0) GLD(Kb + (768+lane)*8, &Ks[buf][0] + 768*8); \
    _Pragma("unroll") \
    for (int c=0;c<2;++c) \
      GLD(Vb + (c*256+tid)*8, &Vs[buf][0] + (c*256+wid*64)*8); \
    if (wid<2) GLD(Vb + (512+tid)*8, &Vs[buf][0] + (512+wid*64)*8); \
  }

  ISSUE(0, 0);
  __syncthreads();

  for (int kt=0; kt<nkt; ++kt){
    const int cur = kt&1;
    const bool more = (kt+1 < nkt);
    if (more) ISSUE(cur^1, kt+1);   // DMA into other buffer, overlaps compute

    // S^T = mfma(K,Q): lane holds q = mi*16 + lrow,
    // kv = (kb>>1)*32 + (lane>>4)*8 + (kb&1)*4 + r  (v8-verified formulas)
    f32x4 st[2][4];
    #pragma unroll
    for (int mi=0;mi<2;++mi)
      #pragma unroll
      for (int kb=0;kb<4;++kb) st[mi][kb] = (f32x4)0.0f;
    #pragma unroll
    for (int kk=0;kk<3;++kk){
      bf16x8 kf[4];
      #pragma unroll
      for (int kb=0;kb<4;++kb)
        kf[kb] = *(const bf16x8*)&Ks[cur][(kb*16+lrow)*104 + kk*32 + lk];
      __builtin_amdgcn_s_setprio(1);
      #pragma unroll
      for (int mi=0;mi<2;++mi)
        #pragma unroll
        for (int kb=0;kb<4;++kb)
          st[mi][kb] = MFMA16(kf[kb], qf[mi][kk], st[mi][kb]);
      __builtin_amdgcn_s_setprio(0);
    }

    // V fragments: XOR-chunk-swizzled read (content identical to v8's)
    bf16x8 vfr[2][5];
    #pragma unroll
    for (int kk=0;kk<2;++kk)
      #pragma unroll
      for (int db=0;db<5;++db){
        int row = db*16 + lrow;
        int ch = ((kk<<2) | (lane>>4)) ^ (row&7);
        vfr[kk][db] = *(const bf16x8*)&Vs[cur][row*64 + (ch<<3)];
      }

    // softmax (no max-tracking; logits bounded) + in-register pack
    bf16x8 pa[2][2];
    #pragma unroll
    for (int mi=0;mi<2;++mi){
      #pragma unroll
      for (int kb=0;kb<4;++kb)
        #pragma unroll
        for (int r=0;r<4;++r)
          st[mi][kb][r] = __builtin_amdgcn_exp2f(st[mi][kb][r]);
      float s0 = (st[mi][0][0]+st[mi][0][1]) + (st[mi][0][2]+st[mi][0][3]);
      float s1 = (st[mi][1][0]+st[mi][1][1]) + (st[mi][1][2]+st[mi][1][3]);
      float s2 = (st[mi][2][0]+st[mi][2][1]) + (st[mi][2][2]+st[mi][2][3]);
      float s3 = (st[mi][3][0]+st[mi][3][1]) + (st[mi][3][2]+st[mi][3][3]);
      l_r[mi] += (s0+s1) + (s2+s3);
      #pragma unroll
      for (int kk=0;kk<2;++kk){
        u32x4 w;
        w.x = cvt_pk_bf16(st[mi][2*kk  ][0], st[mi][2*kk  ][1]);
        w.y = cvt_pk_bf16(st[mi][2*kk  ][2], st[mi][2*kk  ][3]);
        w.z = cvt_pk_bf16(st[mi][2*kk+1][0], st[mi][2*kk+1][1]);
        w.w = cvt_pk_bf16(st[mi][2*kk+1][2], st[mi][2*kk+1][3]);
        pa[mi][kk] = __builtin_bit_cast(bf16x8, w);
      }
    }

    // PV
    __builtin_amdgcn_s_setprio(1);
    #pragma unroll
    for (int mi=0;mi<2;++mi)
      #pragma unroll
      for (int kk=0;kk<2;++kk)
        #pragma unroll
        for (int db=0;db<5;++db)
          o_acc[mi][db] = MFMA16(pa[mi][kk], vfr[kk][db], o_acc[mi][db]);
    __builtin_amdgcn_s_setprio(0);

    if (more) __syncthreads();   // drains DMA (vmcnt) -> buf^1 ready
  }

  // epilogue: reduce l across lane groups (lane&15 = q), redistribute, store
  #pragma unroll
  for (int mi=0;mi<2;++mi){
    float lf = l_r[mi];
    lf += __shfl_xor(lf, 16, 64);
    lf += __shfl_xor(lf, 32, 64);
    #pragma unroll
    for (int r=0;r<4;++r){
      float inv = 1.0f / __shfl(lf, (lane & 48) | (rbase + r), 64);
      int s = qt*128 + wid*32 + mi*16 + rbase + r;
      u16* orow = O + ((size_t)(b*1024 + s))*640 + hh*80;
      #pragma unroll
      for (int db=0;db<5;++db)
        orow[db*16 + lrow] = f2bf(o_acc[mi][db][r]*inv);
    }
  }
  #undef ISSUE
}

// ---------------- launch ----------------
extern "C" void kernel_launch(void* const* d_in, const int* in_sizes, int n_in,
                              void* d_out, int out_size, void* d_ws, size_t ws_size,
                              hipStream_t stream)
{
  const float* x  = (const float*)d_in[0];
  const float* Wq = (const float*)d_in[1];
  const float* Wk = (const float*)d_in[2];
  const float* Wv = (const float*)d_in[3];
  const float* Wo = (const float*)d_in[4];
  const float* bo = (const float*)d_in[5];
  float* out = (float*)d_out;

  char* ws = (char*)d_ws;
  u16* xbf = (u16*)(ws);                 // 15,728,640 B ; reused as Ow after gemm<0>
  u16* wt  = (u16*)(ws + 15728640);      //  2,457,600 B
  u16* wot = (u16*)(ws + 18186240);      //    819,200 B
  u16* Qw  = (u16*)(ws + 19005440);      // 15,728,640 B
  u16* Kg  = (u16*)(ws + 34734080);      // 20,447,232 B  [bh][16][64][104]
  u16* Vg  = (u16*)(ws + 55181312);      // 15,728,640 B  [bh][16][80][64]
  u16* Ow  = xbf;                        // xbf dead after gemm<0>

  cvt_x_kernel<<<7680, 256, 0, stream>>>(x, xbf);
  cvt_w_kernel<<<dim3(20,20,4), dim3(32,8,1), 0, stream>>>(Wq,Wk,Wv,Wo, wt, wot);
  gemm_kernel<0><<<dim3(5,96,3), 256, 0, stream>>>(xbf, wt, nullptr, Qw, Kg, Vg, nullptr);
  attn_kernel<<<768, 256, 0, stream>>>(Qw, Kg, Vg, Ow);
  gemm_kernel<1><<<dim3(5,96,1), 256, 0, stream>>>(Ow, wot, bo, nullptr, nullptr, nullptr, out);
}